// Round 14
// baseline (155.060 us; speedup 1.0000x reference)
//
#include <hip/hip_runtime.h>
#include <hip/hip_bf16.h>

// SupConLoss fused: logits = text @ image^T (bf16 MFMA), masked two-sided
// logsumexp with fixed shift, softplus-mean -> scalar.
// B = N = 8192, D = 256, NUM_CLASSES = 64, T = 1.
//
// R14: split the mask logic out of the main GEMM.
//  - main GEMM (R9 structure): UNIFORM epilogue sumn_raw += exp2(y-72),
//    3 VALU/elem, no labels/compare/routing at all.
//  - positives (1/64 of pairs) handled by a class-indexed mini-GEMM:
//    build_lists bins row/col ids by class; mini_pos gathers fragments by
//    index and computes sump += exp2(-y-72), pcorr += exp2(y-72) for the
//    ~1M positive pairs (1.6% of main FLOPs).
//  - finalize: lse_n from (sumn_raw - pcorr), lse_p from sump.
// R13's divergent branch reverted (per-wave it was taken 63% of the time).

#define B_ROWS   8192
#define N_COLS   8192
#define DIM      256
#define CSPLIT   32                        // grid = (64, 32) = 2048 blocks
#define NTILES   ((N_COLS / CSPLIT) / 32)  // 8 col-tiles of 32 per block
#define BLK_ROWS 128                       // 4 waves x 32 rows
#define THREADS  256
#define NCLS     64
#define CLS_CAP  256                       // >= max class count (128 +/- 11s)

typedef __attribute__((ext_vector_type(8))) short bf16x8;  // 8 bf16 = 4 VGPR
typedef __attribute__((ext_vector_type(4))) float f32x4;   // 16x16 MFMA acc

#if __has_builtin(__builtin_amdgcn_exp2f)
#define EXP2F(x) __builtin_amdgcn_exp2f(x)
#else
#define EXP2F(x) exp2f(x)
#endif
#if __has_builtin(__builtin_amdgcn_logf)
#define LOG2F(x) __builtin_amdgcn_logf(x)
#else
#define LOG2F(x) log2f(x)
#endif

__device__ __forceinline__ unsigned short f2bf(float f) {
    union { float f; unsigned u; } c; c.f = f;
    return (unsigned short)((c.u + 0x7FFFu + ((c.u >> 16) & 1u)) >> 16);
}

// Stage one 16 KB tile (4 x global_load_lds width-16 per thread).
__device__ __forceinline__ void stage_tile(const char* bsrc, char* ldsd,
                                           int T, int BUF) {
#pragma unroll
    for (int i_ = 0; i_ < 4; ++i_)
        __builtin_amdgcn_global_load_lds(
            (const __attribute__((address_space(1))) unsigned int*)
                (bsrc + (size_t)T * 16384 + i_ * 4096),
            (__attribute__((address_space(3))) unsigned int*)
                (ldsd + (size_t)BUF * 16384 + i_ * 4096),
            16, 0, 0);
}

// One dispatch: zero {gsum_p, gsum_n, gsum_pc, rcnt, ccnt} (6176 float4),
// cvt A (row-major bf16, PRE-SCALED by log2e so MFMA yields y = x*log2e),
// cvt+transpose B into Bt (group g, chunk c holds
// B[g*32+(c&31)][k=(c>>5)*8..+8)).
__global__ void cvt_all_kernel(const float* __restrict__ text,
                               const float* __restrict__ img,
                               unsigned short* __restrict__ Abf,
                               unsigned short* __restrict__ Bt,
                               float* __restrict__ zero_base) {
    const float L2E = 1.4426950408889634f;
    const int i = blockIdx.x * blockDim.x + threadIdx.x;   // [0, 524288)
    if (i < 6176) {   // 24576 floats gsum + 128 ints counters
        reinterpret_cast<float4*>(zero_base)[i] = float4{0.f, 0.f, 0.f, 0.f};
    }
    if (i < 262144) {
        const float4* src = reinterpret_cast<const float4*>(text) + i * 2;
        float4 v0 = src[0], v1 = src[1];
        unsigned short s[8];
        s[0] = f2bf(v0.x * L2E); s[1] = f2bf(v0.y * L2E);
        s[2] = f2bf(v0.z * L2E); s[3] = f2bf(v0.w * L2E);
        s[4] = f2bf(v1.x * L2E); s[5] = f2bf(v1.y * L2E);
        s[6] = f2bf(v1.z * L2E); s[7] = f2bf(v1.w * L2E);
        reinterpret_cast<bf16x8*>(Abf)[i] = *reinterpret_cast<const bf16x8*>(s);
    } else {
        const int C = i - 262144;           // Bt chunk id, [0, 262144)
        const int g = C >> 10, c = C & 1023;
        const int col = g * 32 + (c & 31);
        const int k8  = c >> 5;
        const float4* src =
            reinterpret_cast<const float4*>(img + (size_t)col * DIM + k8 * 8);
        float4 v0 = src[0], v1 = src[1];
        unsigned short s[8];
        s[0] = f2bf(v0.x); s[1] = f2bf(v0.y); s[2] = f2bf(v0.z); s[3] = f2bf(v0.w);
        s[4] = f2bf(v1.x); s[5] = f2bf(v1.y); s[6] = f2bf(v1.z); s[7] = f2bf(v1.w);
        reinterpret_cast<bf16x8*>(Bt)[C] = *reinterpret_cast<const bf16x8*>(s);
    }
}

// Bin row / col indices by class (slot order irrelevant).
__global__ void build_lists_kernel(const int* __restrict__ tlab,
                                   const int* __restrict__ itgt,
                                   int* __restrict__ rcnt,
                                   int* __restrict__ ccnt,
                                   int* __restrict__ cls_rows,
                                   int* __restrict__ cls_cols) {
    const int i = blockIdx.x * blockDim.x + threadIdx.x;   // [0, 16384)
    if (i < B_ROWS) {
        const int c = tlab[i] & (NCLS - 1);
        const int s = atomicAdd(&rcnt[c], 1);
        if (s < CLS_CAP) cls_rows[c * CLS_CAP + s] = i;
    } else {
        const int j = i - B_ROWS;
        const int c = itgt[j] & (NCLS - 1);
        const int s = atomicAdd(&ccnt[c], 1);
        if (s < CLS_CAP) cls_cols[c * CLS_CAP + s] = j;
    }
}

// mfma_f32_16x16x32_bf16 layouts (R5-verified, absmax 0.0):
//   A: row = lane&15, k = 8*(lane>>4)+j
//   B: col = lane&15, k = 8*(lane>>4)+j
//   C: col = lane&15, row = (lane>>4)*4 + j
// LDS tile (16 KB): chunk c=(k8*32+col) at byte c*16.
__launch_bounds__(THREADS, 3)
__global__ void fused_gemm_lse(const unsigned short* __restrict__ Abf,
                               const unsigned short* __restrict__ Bt,
                               float* __restrict__ gsum_n) {
    __shared__ char lds[2 * 16384] __attribute__((aligned(128)));

    const int tid  = threadIdx.x;
    const int lane = tid & 63;
    const int wave = tid >> 6;
    const int l15  = lane & 15;
    const int q    = lane >> 4;
    const int rb   = blockIdx.x * BLK_ROWS + wave * 32;

    bf16x8 afrag0[8], afrag1[8];
    const bf16x8* arow0 =
        reinterpret_cast<const bf16x8*>(Abf + (size_t)(rb + l15) * DIM) + q;
    const bf16x8* arow1 =
        reinterpret_cast<const bf16x8*>(Abf + (size_t)(rb + 16 + l15) * DIM) + q;
#pragma unroll
    for (int ks = 0; ks < 8; ++ks) {
        afrag0[ks] = arow0[ks * 4];
        afrag1[ks] = arow1[ks * 4];
    }

    float sumn0[4] = {0, 0, 0, 0};
    float sumn1[4] = {0, 0, 0, 0};

    const char* bsrc = (const char*)Bt
        + ((size_t)blockIdx.y * NTILES) * 16384 + tid * 16;
    char* ldsd = lds + tid * 16;

    stage_tile(bsrc, ldsd, 0, 0);

    for (int t = 0; t < NTILES; ++t) {
        __syncthreads();   // tile t staged; buffer t+1 free to overwrite
        if (t + 1 < NTILES) stage_tile(bsrc, ldsd, t + 1, (t + 1) & 1);

        f32x4 acc00 = {0, 0, 0, 0}, acc01 = {0, 0, 0, 0};
        f32x4 acc10 = {0, 0, 0, 0}, acc11 = {0, 0, 0, 0};
        const char* bb = lds + (t & 1) * 16384 + q * 512 + l15 * 16;
#pragma unroll
        for (int ks = 0; ks < 8; ++ks) {
            bf16x8 b0 = *reinterpret_cast<const bf16x8*>(bb + ks * 2048);
            bf16x8 b1 = *reinterpret_cast<const bf16x8*>(bb + ks * 2048 + 256);
            acc00 = __builtin_amdgcn_mfma_f32_16x16x32_bf16(afrag0[ks], b0,
                                                            acc00, 0, 0, 0);
            acc01 = __builtin_amdgcn_mfma_f32_16x16x32_bf16(afrag0[ks], b1,
                                                            acc01, 0, 0, 0);
            acc10 = __builtin_amdgcn_mfma_f32_16x16x32_bf16(afrag1[ks], b0,
                                                            acc10, 0, 0, 0);
            acc11 = __builtin_amdgcn_mfma_f32_16x16x32_bf16(afrag1[ks], b1,
                                                            acc11, 0, 0, 0);
        }

        // UNIFORM epilogue: no labels, no compare, no routing.
#pragma unroll
        for (int j = 0; j < 4; ++j) {
            sumn0[j] += EXP2F(acc00[j] - 72.0f) + EXP2F(acc01[j] - 72.0f);
            sumn1[j] += EXP2F(acc10[j] - 72.0f) + EXP2F(acc11[j] - 72.0f);
        }
    }

    // Reduce over the 16 cols of each quarter-wave, one atomic per row.
#pragma unroll
    for (int j = 0; j < 4; ++j) {
        float vn0 = sumn0[j], vn1 = sumn1[j];
#pragma unroll
        for (int m = 1; m < 16; m <<= 1) {
            vn0 += __shfl_xor(vn0, m, 64);
            vn1 += __shfl_xor(vn1, m, 64);
        }
        if (l15 == 0) {
            atomicAdd(&gsum_n[rb + q * 4 + j], vn0);
            atomicAdd(&gsum_n[rb + 16 + q * 4 + j], vn1);
        }
    }
}

// Positive pairs only: one block per class; gathered-fragment MFMA over
// rows_of_class x cols_of_class (~128x128). For each positive pair:
// sump += exp2(-y-72) (for lse_p), pcorr += exp2(y-72) (to subtract the
// positive contributions out of the uniform sumn_raw).
__launch_bounds__(THREADS, 2)
__global__ void mini_pos_kernel(const unsigned short* __restrict__ Abf,
                                const unsigned short* __restrict__ Bt,
                                const int* __restrict__ rcnt,
                                const int* __restrict__ ccnt,
                                const int* __restrict__ cls_rows,
                                const int* __restrict__ cls_cols,
                                float* __restrict__ gsum_p,
                                float* __restrict__ gsum_pc) {
    const int c  = blockIdx.x;
    const int rc = min(rcnt[c], CLS_CAP);
    const int cn = min(ccnt[c], CLS_CAP);
    if (rc == 0 || cn == 0) return;
    const int rt = (rc + 31) >> 5, ct = (cn + 31) >> 5;

    const int tid  = threadIdx.x;
    const int lane = tid & 63;
    const int wave = tid >> 6;
    const int l15  = lane & 15;
    const int q    = lane >> 4;
    const int* rl = cls_rows + c * CLS_CAP;
    const int* cl = cls_cols + c * CLS_CAP;

    int task = 0;
    for (int a = 0; a < rt; ++a) {
        for (int b = 0; b < ct; ++b, ++task) {
            if ((task & 3) != wave) continue;

            const int r0 = rl[min(a * 32 + l15, rc - 1)];
            const int r1 = rl[min(a * 32 + 16 + l15, rc - 1)];
            const int c0 = cl[min(b * 32 + l15, cn - 1)];
            const int c1 = cl[min(b * 32 + 16 + l15, cn - 1)];
            const bool cv0 = (b * 32 + l15) < cn;
            const bool cv1 = (b * 32 + 16 + l15) < cn;

            const bf16x8* a0p =
                reinterpret_cast<const bf16x8*>(Abf + (size_t)r0 * DIM) + q;
            const bf16x8* a1p =
                reinterpret_cast<const bf16x8*>(Abf + (size_t)r1 * DIM) + q;
            const char* b0p = (const char*)Bt + (size_t)(c0 >> 5) * 16384
                              + (c0 & 31) * 16 + q * 512;
            const char* b1p = (const char*)Bt + (size_t)(c1 >> 5) * 16384
                              + (c1 & 31) * 16 + q * 512;

            f32x4 acc00 = {0, 0, 0, 0}, acc01 = {0, 0, 0, 0};
            f32x4 acc10 = {0, 0, 0, 0}, acc11 = {0, 0, 0, 0};
#pragma unroll
            for (int ks = 0; ks < 8; ++ks) {
                bf16x8 a0 = a0p[ks * 4], a1 = a1p[ks * 4];
                bf16x8 b0 = *reinterpret_cast<const bf16x8*>(b0p + ks * 2048);
                bf16x8 b1 = *reinterpret_cast<const bf16x8*>(b1p + ks * 2048);
                acc00 = __builtin_amdgcn_mfma_f32_16x16x32_bf16(a0, b0, acc00,
                                                                0, 0, 0);
                acc01 = __builtin_amdgcn_mfma_f32_16x16x32_bf16(a0, b1, acc01,
                                                                0, 0, 0);
                acc10 = __builtin_amdgcn_mfma_f32_16x16x32_bf16(a1, b0, acc10,
                                                                0, 0, 0);
                acc11 = __builtin_amdgcn_mfma_f32_16x16x32_bf16(a1, b1, acc11,
                                                                0, 0, 0);
            }

#pragma unroll
            for (int j = 0; j < 4; ++j) {
                // row-tile 0
                {
                    const int rp = a * 32 + q * 4 + j;
                    const bool rv = rp < rc;
                    const float y0 = acc00[j], y1 = acc01[j];
                    float uu = ((rv && cv0) ? EXP2F(y0 - 72.0f) : 0.f)
                             + ((rv && cv1) ? EXP2F(y1 - 72.0f) : 0.f);
                    float vv = ((rv && cv0) ? EXP2F(-y0 - 72.0f) : 0.f)
                             + ((rv && cv1) ? EXP2F(-y1 - 72.0f) : 0.f);
#pragma unroll
                    for (int m = 1; m < 16; m <<= 1) {
                        uu += __shfl_xor(uu, m, 64);
                        vv += __shfl_xor(vv, m, 64);
                    }
                    if (l15 == 0 && rv) {
                        const int rg = rl[rp];
                        atomicAdd(&gsum_p[rg], vv);
                        atomicAdd(&gsum_pc[rg], uu);
                    }
                }
                // row-tile 1
                {
                    const int rp = a * 32 + 16 + q * 4 + j;
                    const bool rv = rp < rc;
                    const float y0 = acc10[j], y1 = acc11[j];
                    float uu = ((rv && cv0) ? EXP2F(y0 - 72.0f) : 0.f)
                             + ((rv && cv1) ? EXP2F(y1 - 72.0f) : 0.f);
                    float vv = ((rv && cv0) ? EXP2F(-y0 - 72.0f) : 0.f)
                             + ((rv && cv1) ? EXP2F(-y1 - 72.0f) : 0.f);
#pragma unroll
                    for (int m = 1; m < 16; m <<= 1) {
                        uu += __shfl_xor(uu, m, 64);
                        vv += __shfl_xor(vv, m, 64);
                    }
                    if (l15 == 0 && rv) {
                        const int rg = rl[rp];
                        atomicAdd(&gsum_p[rg], vv);
                        atomicAdd(&gsum_pc[rg], uu);
                    }
                }
            }
        }
    }
}

// lse_p = (log2(sump)+72)*ln2 ; lse_n = (log2(sumn_raw - pcorr)+72)*ln2 ;
// loss = mean softplus(lse_p + lse_n)
__global__ void finalize_kernel(const float* __restrict__ gsum_p,
                                const float* __restrict__ gsum_n,
                                const float* __restrict__ gsum_pc,
                                float* __restrict__ out) {
    __shared__ float red[1024];
    const float LN2 = 0.6931471805599453f;
    const float C2  = 72.0f;
    float acc = 0.f;
    for (int i = threadIdx.x; i < B_ROWS; i += 1024) {
        const float sn = fmaxf(gsum_n[i] - gsum_pc[i], 1e-38f);
        float zp = (LOG2F(gsum_p[i]) + C2) * LN2;
        float zn = (LOG2F(sn) + C2) * LN2;
        float z  = zp + zn;
        float sp = fmaxf(z, 0.f) + log1pf(expf(-fabsf(z)));
        acc += sp;
    }
    red[threadIdx.x] = acc;
    __syncthreads();
    for (int s = 512; s > 0; s >>= 1) {
        if ((int)threadIdx.x < s) red[threadIdx.x] += red[threadIdx.x + s];
        __syncthreads();
    }
    if (threadIdx.x == 0) out[0] = red[0] / (float)B_ROWS;
}

extern "C" void kernel_launch(void* const* d_in, const int* in_sizes, int n_in,
                              void* d_out, int out_size, void* d_ws, size_t ws_size,
                              hipStream_t stream) {
    const float* text = (const float*)d_in[0];   // [B, D] f32
    const float* img  = (const float*)d_in[1];   // [N, D] f32
    const int* tlab   = (const int*)d_in[2];     // [B]
    const int* itgt   = (const int*)d_in[3];     // [N]
    float* out        = (float*)d_out;           // scalar f32

    char* ws = (char*)d_ws;
    unsigned short* Abf = (unsigned short*)(ws);                            // 4 MB
    unsigned short* Bt  = (unsigned short*)(ws + (size_t)B_ROWS * DIM * 2); // 4 MB
    char* base2 = ws + (size_t)(B_ROWS + N_COLS) * DIM * 2;   // +8 MB
    float* gsum_p  = (float*)(base2);                 // 8192 f
    float* gsum_n  = gsum_p + B_ROWS;                 // 8192 f
    float* gsum_pc = gsum_n + B_ROWS;                 // 8192 f
    int*   rcnt    = (int*)(gsum_pc + B_ROWS);        // 64
    int*   ccnt    = rcnt + NCLS;                     // 64
    int*   cls_rows = ccnt + NCLS;                    // 64*256
    int*   cls_cols = cls_rows + NCLS * CLS_CAP;      // 64*256

    // zero region = gsum_p..ccnt = 3*8192 floats + 128 ints = 6176 float4
    cvt_all_kernel<<<(2 * 262144) / 256, 256, 0, stream>>>(text, img, Abf, Bt,
                                                           gsum_p);

    build_lists_kernel<<<(2 * B_ROWS) / 256, 256, 0, stream>>>(
        tlab, itgt, rcnt, ccnt, cls_rows, cls_cols);

    mini_pos_kernel<<<NCLS, THREADS, 0, stream>>>(Abf, Bt, rcnt, ccnt,
                                                  cls_rows, cls_cols,
                                                  gsum_p, gsum_pc);

    dim3 grid(B_ROWS / BLK_ROWS, CSPLIT);
    fused_gemm_lse<<<grid, THREADS, 0, stream>>>(Abf, Bt, gsum_n);

    finalize_kernel<<<1, 1024, 0, stream>>>(gsum_p, gsum_n, gsum_pc, out);
}

// Round 15
// 92.787 us; speedup vs baseline: 1.6711x; 1.6711x over previous
//
#include <hip/hip_runtime.h>
#include <hip/hip_bf16.h>

// SupConLoss fused: logits = text @ image^T (bf16 MFMA), masked two-sided
// logsumexp with fixed shift, softplus-mean -> scalar.
// B = N = 8192, D = 256, NUM_CLASSES = 64, T = 1.
//
// R15 = R14 with the two regressions fixed:
//  (1) #pragma unroll 1 on the main GEMM tile loop. R14's uniform epilogue
//      made the loop fully-unrollable -> LLVM unrolled NTILES=8 and spilled
//      (WRITE_SIZE 8->75 MB). The R11 probe (same body + unroll 1) ran
//      28.5us/pass with VGPR 48 and zero spill -- that's the proven config.
//  (2) mini_pos parallelized: grid (NCLS x 4), wave-task stride 16 (R14 ran
//      64 blocks with serial task loops -> ~55us; now ~1024 parallel tasks).
// Main-GEMM epilogue is label-free: sumn_raw += exp2(y-72) for ALL pairs;
// positives (1/64) handled by the class-indexed mini-GEMM which computes
// sump += exp2(-y-72) and pcorr += exp2(y-72); finalize subtracts pcorr.

#define B_ROWS   8192
#define N_COLS   8192
#define DIM      256
#define CSPLIT   32                        // grid = (64, 32) = 2048 blocks
#define NTILES   ((N_COLS / CSPLIT) / 32)  // 8 col-tiles of 32 per block
#define BLK_ROWS 128                       // 4 waves x 32 rows
#define THREADS  256
#define NCLS     64
#define CLS_CAP  256                       // >= max per-class count

typedef __attribute__((ext_vector_type(8))) short bf16x8;  // 8 bf16 = 4 VGPR
typedef __attribute__((ext_vector_type(4))) float f32x4;   // 16x16 MFMA acc

#if __has_builtin(__builtin_amdgcn_exp2f)
#define EXP2F(x) __builtin_amdgcn_exp2f(x)
#else
#define EXP2F(x) exp2f(x)
#endif
#if __has_builtin(__builtin_amdgcn_logf)
#define LOG2F(x) __builtin_amdgcn_logf(x)
#else
#define LOG2F(x) log2f(x)
#endif

__device__ __forceinline__ unsigned short f2bf(float f) {
    union { float f; unsigned u; } c; c.f = f;
    return (unsigned short)((c.u + 0x7FFFu + ((c.u >> 16) & 1u)) >> 16);
}

// Stage one 16 KB tile (4 x global_load_lds width-16 per thread).
__device__ __forceinline__ void stage_tile(const char* bsrc, char* ldsd,
                                           int T, int BUF) {
#pragma unroll
    for (int i_ = 0; i_ < 4; ++i_)
        __builtin_amdgcn_global_load_lds(
            (const __attribute__((address_space(1))) unsigned int*)
                (bsrc + (size_t)T * 16384 + i_ * 4096),
            (__attribute__((address_space(3))) unsigned int*)
                (ldsd + (size_t)BUF * 16384 + i_ * 4096),
            16, 0, 0);
}

// One dispatch: zero {gsum_p, gsum_n, gsum_pc, rcnt, ccnt}, cvt A (bf16,
// PRE-SCALED by log2e so MFMA yields y = x*log2e), cvt+transpose B into Bt
// (group g, chunk c holds B[g*32+(c&31)][k=(c>>5)*8..+8)).
__global__ void cvt_all_kernel(const float* __restrict__ text,
                               const float* __restrict__ img,
                               unsigned short* __restrict__ Abf,
                               unsigned short* __restrict__ Bt,
                               float* __restrict__ zero_base) {
    const float L2E = 1.4426950408889634f;
    const int i = blockIdx.x * blockDim.x + threadIdx.x;   // [0, 524288)
    if (i < 6176) {   // 3*8192 floats gsum + 128 ints counters
        reinterpret_cast<float4*>(zero_base)[i] = float4{0.f, 0.f, 0.f, 0.f};
    }
    if (i < 262144) {
        const float4* src = reinterpret_cast<const float4*>(text) + i * 2;
        float4 v0 = src[0], v1 = src[1];
        unsigned short s[8];
        s[0] = f2bf(v0.x * L2E); s[1] = f2bf(v0.y * L2E);
        s[2] = f2bf(v0.z * L2E); s[3] = f2bf(v0.w * L2E);
        s[4] = f2bf(v1.x * L2E); s[5] = f2bf(v1.y * L2E);
        s[6] = f2bf(v1.z * L2E); s[7] = f2bf(v1.w * L2E);
        reinterpret_cast<bf16x8*>(Abf)[i] = *reinterpret_cast<const bf16x8*>(s);
    } else {
        const int C = i - 262144;           // Bt chunk id, [0, 262144)
        const int g = C >> 10, c = C & 1023;
        const int col = g * 32 + (c & 31);
        const int k8  = c >> 5;
        const float4* src =
            reinterpret_cast<const float4*>(img + (size_t)col * DIM + k8 * 8);
        float4 v0 = src[0], v1 = src[1];
        unsigned short s[8];
        s[0] = f2bf(v0.x); s[1] = f2bf(v0.y); s[2] = f2bf(v0.z); s[3] = f2bf(v0.w);
        s[4] = f2bf(v1.x); s[5] = f2bf(v1.y); s[6] = f2bf(v1.z); s[7] = f2bf(v1.w);
        reinterpret_cast<bf16x8*>(Bt)[C] = *reinterpret_cast<const bf16x8*>(s);
    }
}

// Bin row / col indices by class (slot order irrelevant).
__global__ void build_lists_kernel(const int* __restrict__ tlab,
                                   const int* __restrict__ itgt,
                                   int* __restrict__ rcnt,
                                   int* __restrict__ ccnt,
                                   int* __restrict__ cls_rows,
                                   int* __restrict__ cls_cols) {
    const int i = blockIdx.x * blockDim.x + threadIdx.x;   // [0, 16384)
    if (i < B_ROWS) {
        const int c = tlab[i] & (NCLS - 1);
        const int s = atomicAdd(&rcnt[c], 1);
        if (s < CLS_CAP) cls_rows[c * CLS_CAP + s] = i;
    } else {
        const int j = i - B_ROWS;
        const int c = itgt[j] & (NCLS - 1);
        const int s = atomicAdd(&ccnt[c], 1);
        if (s < CLS_CAP) cls_cols[c * CLS_CAP + s] = j;
    }
}

// mfma_f32_16x16x32_bf16 layouts (R5-verified, absmax 0.0):
//   A: row = lane&15, k = 8*(lane>>4)+j
//   B: col = lane&15, k = 8*(lane>>4)+j
//   C: col = lane&15, row = (lane>>4)*4 + j
// LDS tile (16 KB): chunk c=(k8*32+col) at byte c*16.
__launch_bounds__(THREADS, 3)
__global__ void fused_gemm_lse(const unsigned short* __restrict__ Abf,
                               const unsigned short* __restrict__ Bt,
                               float* __restrict__ gsum_n) {
    __shared__ char lds[2 * 16384] __attribute__((aligned(128)));

    const int tid  = threadIdx.x;
    const int lane = tid & 63;
    const int wave = tid >> 6;
    const int l15  = lane & 15;
    const int q    = lane >> 4;
    const int rb   = blockIdx.x * BLK_ROWS + wave * 32;

    bf16x8 afrag0[8], afrag1[8];
    const bf16x8* arow0 =
        reinterpret_cast<const bf16x8*>(Abf + (size_t)(rb + l15) * DIM) + q;
    const bf16x8* arow1 =
        reinterpret_cast<const bf16x8*>(Abf + (size_t)(rb + 16 + l15) * DIM) + q;
#pragma unroll
    for (int ks = 0; ks < 8; ++ks) {
        afrag0[ks] = arow0[ks * 4];
        afrag1[ks] = arow1[ks * 4];
    }

    float sumn0[4] = {0, 0, 0, 0};
    float sumn1[4] = {0, 0, 0, 0};

    const char* bsrc = (const char*)Bt
        + ((size_t)blockIdx.y * NTILES) * 16384 + tid * 16;
    char* ldsd = lds + tid * 16;

    stage_tile(bsrc, ldsd, 0, 0);

    // unroll 1: the R11 probe proved this exact loop shape runs spill-free
    // at MfmaUtil 53% (VGPR 48); full unroll was R14's 75MB-spill cause.
#pragma unroll 1
    for (int t = 0; t < NTILES; ++t) {
        __syncthreads();   // tile t staged; buffer t+1 free to overwrite
        if (t + 1 < NTILES) stage_tile(bsrc, ldsd, t + 1, (t + 1) & 1);

        f32x4 acc00 = {0, 0, 0, 0}, acc01 = {0, 0, 0, 0};
        f32x4 acc10 = {0, 0, 0, 0}, acc11 = {0, 0, 0, 0};
        const char* bb = lds + (t & 1) * 16384 + q * 512 + l15 * 16;
#pragma unroll
        for (int ks = 0; ks < 8; ++ks) {
            bf16x8 b0 = *reinterpret_cast<const bf16x8*>(bb + ks * 2048);
            bf16x8 b1 = *reinterpret_cast<const bf16x8*>(bb + ks * 2048 + 256);
            acc00 = __builtin_amdgcn_mfma_f32_16x16x32_bf16(afrag0[ks], b0,
                                                            acc00, 0, 0, 0);
            acc01 = __builtin_amdgcn_mfma_f32_16x16x32_bf16(afrag0[ks], b1,
                                                            acc01, 0, 0, 0);
            acc10 = __builtin_amdgcn_mfma_f32_16x16x32_bf16(afrag1[ks], b0,
                                                            acc10, 0, 0, 0);
            acc11 = __builtin_amdgcn_mfma_f32_16x16x32_bf16(afrag1[ks], b1,
                                                            acc11, 0, 0, 0);
        }

        // UNIFORM epilogue: no labels, no compare, no routing.
#pragma unroll
        for (int j = 0; j < 4; ++j) {
            sumn0[j] += EXP2F(acc00[j] - 72.0f) + EXP2F(acc01[j] - 72.0f);
            sumn1[j] += EXP2F(acc10[j] - 72.0f) + EXP2F(acc11[j] - 72.0f);
        }
    }

    // Reduce over the 16 cols of each quarter-wave, one atomic per row.
#pragma unroll
    for (int j = 0; j < 4; ++j) {
        float vn0 = sumn0[j], vn1 = sumn1[j];
#pragma unroll
        for (int m = 1; m < 16; m <<= 1) {
            vn0 += __shfl_xor(vn0, m, 64);
            vn1 += __shfl_xor(vn1, m, 64);
        }
        if (l15 == 0) {
            atomicAdd(&gsum_n[rb + q * 4 + j], vn0);
            atomicAdd(&gsum_n[rb + 16 + q * 4 + j], vn1);
        }
    }
}

// Positive pairs only, parallelized: grid (NCLS, 4) x 4 waves = 16 wave
// slots per class; wave slot handles tasks (a,b) with stride 16. For each
// positive pair: sump += exp2(-y-72), pcorr += exp2(y-72).
__launch_bounds__(THREADS, 2)
__global__ void mini_pos_kernel(const unsigned short* __restrict__ Abf,
                                const unsigned short* __restrict__ Bt,
                                const int* __restrict__ rcnt,
                                const int* __restrict__ ccnt,
                                const int* __restrict__ cls_rows,
                                const int* __restrict__ cls_cols,
                                float* __restrict__ gsum_p,
                                float* __restrict__ gsum_pc) {
    const int c  = blockIdx.x;
    const int rc = min(rcnt[c], CLS_CAP);
    const int cn = min(ccnt[c], CLS_CAP);
    if (rc == 0 || cn == 0) return;
    const int rt = (rc + 31) >> 5, ct = (cn + 31) >> 5;
    const int ntask = rt * ct;

    const int tid  = threadIdx.x;
    const int lane = tid & 63;
    const int wave = tid >> 6;
    const int slot = blockIdx.y * 4 + wave;    // [0, 16)
    const int l15  = lane & 15;
    const int q    = lane >> 4;
    const int* rl = cls_rows + c * CLS_CAP;
    const int* cl = cls_cols + c * CLS_CAP;

#pragma unroll 1
    for (int task = slot; task < ntask; task += 16) {
        const int a = task / ct;
        const int b = task - a * ct;

        const int r0 = rl[min(a * 32 + l15, rc - 1)];
        const int r1 = rl[min(a * 32 + 16 + l15, rc - 1)];
        const int c0 = cl[min(b * 32 + l15, cn - 1)];
        const int c1 = cl[min(b * 32 + 16 + l15, cn - 1)];
        const bool cv0 = (b * 32 + l15) < cn;
        const bool cv1 = (b * 32 + 16 + l15) < cn;

        const bf16x8* a0p =
            reinterpret_cast<const bf16x8*>(Abf + (size_t)r0 * DIM) + q;
        const bf16x8* a1p =
            reinterpret_cast<const bf16x8*>(Abf + (size_t)r1 * DIM) + q;
        const char* b0p = (const char*)Bt + (size_t)(c0 >> 5) * 16384
                          + (c0 & 31) * 16 + q * 512;
        const char* b1p = (const char*)Bt + (size_t)(c1 >> 5) * 16384
                          + (c1 & 31) * 16 + q * 512;

        f32x4 acc00 = {0, 0, 0, 0}, acc01 = {0, 0, 0, 0};
        f32x4 acc10 = {0, 0, 0, 0}, acc11 = {0, 0, 0, 0};
#pragma unroll
        for (int ks = 0; ks < 8; ++ks) {
            bf16x8 a0 = a0p[ks * 4], a1 = a1p[ks * 4];
            bf16x8 b0 = *reinterpret_cast<const bf16x8*>(b0p + ks * 2048);
            bf16x8 b1 = *reinterpret_cast<const bf16x8*>(b1p + ks * 2048);
            acc00 = __builtin_amdgcn_mfma_f32_16x16x32_bf16(a0, b0, acc00,
                                                            0, 0, 0);
            acc01 = __builtin_amdgcn_mfma_f32_16x16x32_bf16(a0, b1, acc01,
                                                            0, 0, 0);
            acc10 = __builtin_amdgcn_mfma_f32_16x16x32_bf16(a1, b0, acc10,
                                                            0, 0, 0);
            acc11 = __builtin_amdgcn_mfma_f32_16x16x32_bf16(a1, b1, acc11,
                                                            0, 0, 0);
        }

#pragma unroll
        for (int j = 0; j < 4; ++j) {
            // row-tile 0
            {
                const int rp = a * 32 + q * 4 + j;
                const bool rv = rp < rc;
                const float y0 = acc00[j], y1 = acc01[j];
                float uu = ((rv && cv0) ? EXP2F(y0 - 72.0f) : 0.f)
                         + ((rv && cv1) ? EXP2F(y1 - 72.0f) : 0.f);
                float vv = ((rv && cv0) ? EXP2F(-y0 - 72.0f) : 0.f)
                         + ((rv && cv1) ? EXP2F(-y1 - 72.0f) : 0.f);
#pragma unroll
                for (int m = 1; m < 16; m <<= 1) {
                    uu += __shfl_xor(uu, m, 64);
                    vv += __shfl_xor(vv, m, 64);
                }
                if (l15 == 0 && rv) {
                    const int rg = rl[rp];
                    atomicAdd(&gsum_p[rg], vv);
                    atomicAdd(&gsum_pc[rg], uu);
                }
            }
            // row-tile 1
            {
                const int rp = a * 32 + 16 + q * 4 + j;
                const bool rv = rp < rc;
                const float y0 = acc10[j], y1 = acc11[j];
                float uu = ((rv && cv0) ? EXP2F(y0 - 72.0f) : 0.f)
                         + ((rv && cv1) ? EXP2F(y1 - 72.0f) : 0.f);
                float vv = ((rv && cv0) ? EXP2F(-y0 - 72.0f) : 0.f)
                         + ((rv && cv1) ? EXP2F(-y1 - 72.0f) : 0.f);
#pragma unroll
                for (int m = 1; m < 16; m <<= 1) {
                    uu += __shfl_xor(uu, m, 64);
                    vv += __shfl_xor(vv, m, 64);
                }
                if (l15 == 0 && rv) {
                    const int rg = rl[rp];
                    atomicAdd(&gsum_p[rg], vv);
                    atomicAdd(&gsum_pc[rg], uu);
                }
            }
        }
    }
}

// lse_p = (log2(sump)+72)*ln2 ; lse_n = (log2(sumn_raw - pcorr)+72)*ln2 ;
// loss = mean softplus(lse_p + lse_n)
__global__ void finalize_kernel(const float* __restrict__ gsum_p,
                                const float* __restrict__ gsum_n,
                                const float* __restrict__ gsum_pc,
                                float* __restrict__ out) {
    __shared__ float red[1024];
    const float LN2 = 0.6931471805599453f;
    const float C2  = 72.0f;
    float acc = 0.f;
    for (int i = threadIdx.x; i < B_ROWS; i += 1024) {
        const float sn = fmaxf(gsum_n[i] - gsum_pc[i], 1e-38f);
        float zp = (LOG2F(gsum_p[i]) + C2) * LN2;
        float zn = (LOG2F(sn) + C2) * LN2;
        float z  = zp + zn;
        float sp = fmaxf(z, 0.f) + log1pf(expf(-fabsf(z)));
        acc += sp;
    }
    red[threadIdx.x] = acc;
    __syncthreads();
    for (int s = 512; s > 0; s >>= 1) {
        if ((int)threadIdx.x < s) red[threadIdx.x] += red[threadIdx.x + s];
        __syncthreads();
    }
    if (threadIdx.x == 0) out[0] = red[0] / (float)B_ROWS;
}

extern "C" void kernel_launch(void* const* d_in, const int* in_sizes, int n_in,
                              void* d_out, int out_size, void* d_ws, size_t ws_size,
                              hipStream_t stream) {
    const float* text = (const float*)d_in[0];   // [B, D] f32
    const float* img  = (const float*)d_in[1];   // [N, D] f32
    const int* tlab   = (const int*)d_in[2];     // [B]
    const int* itgt   = (const int*)d_in[3];     // [N]
    float* out        = (float*)d_out;           // scalar f32

    char* ws = (char*)d_ws;
    unsigned short* Abf = (unsigned short*)(ws);                            // 4 MB
    unsigned short* Bt  = (unsigned short*)(ws + (size_t)B_ROWS * DIM * 2); // 4 MB
    char* base2 = ws + (size_t)(B_ROWS + N_COLS) * DIM * 2;   // +8 MB
    float* gsum_p  = (float*)(base2);                 // 8192 f
    float* gsum_n  = gsum_p + B_ROWS;                 // 8192 f
    float* gsum_pc = gsum_n + B_ROWS;                 // 8192 f
    int*   rcnt    = (int*)(gsum_pc + B_ROWS);        // 64
    int*   ccnt    = rcnt + NCLS;                     // 64
    int*   cls_rows = ccnt + NCLS;                    // 64*256
    int*   cls_cols = cls_rows + NCLS * CLS_CAP;      // 64*256

    cvt_all_kernel<<<(2 * 262144) / 256, 256, 0, stream>>>(text, img, Abf, Bt,
                                                           gsum_p);

    build_lists_kernel<<<(2 * B_ROWS) / 256, 256, 0, stream>>>(
        tlab, itgt, rcnt, ccnt, cls_rows, cls_cols);

    mini_pos_kernel<<<dim3(NCLS, 4), THREADS, 0, stream>>>(
        Abf, Bt, rcnt, ccnt, cls_rows, cls_cols, gsum_p, gsum_pc);

    dim3 grid(B_ROWS / BLK_ROWS, CSPLIT);
    fused_gemm_lse<<<grid, THREADS, 0, stream>>>(Abf, Bt, gsum_n);

    finalize_kernel<<<1, 1024, 0, stream>>>(gsum_p, gsum_n, gsum_pc, out);
}